// Round 11
// baseline (354.613 us; speedup 1.0000x reference)
//
#include <hip/hip_runtime.h>
#include <hip/hip_bf16.h>
#include <stdint.h>

#define N_USER 100000
#define M_ITEM 50000
#define N_NODE 150000
#define B_SEED 2048
#define S_NB 20
#define UBLK2 1563           // ceil(100000/64)
#define IBLK2 782            // ceil(50000/64)

typedef __bf16   bf16x8 __attribute__((ext_vector_type(8)));
typedef float    f32x4  __attribute__((ext_vector_type(4)));
typedef uint32_t u32x4  __attribute__((ext_vector_type(4)));

typedef __attribute__((address_space(3))) uint32_t lds_u32_t;
typedef __attribute__((address_space(1))) const uint32_t glb_u32_t;

__device__ __forceinline__ uint16_t f2bf(float f) {
    uint32_t u = __float_as_uint(f);
    return (uint16_t)((u + 0x7FFFu + ((u >> 16) & 1u)) >> 16);   // RNE
}
__device__ __forceinline__ uint32_t pk2(float a, float b) {      // packed HW cvt (RNE)
    __hip_bfloat162 h = __float22bfloat162_rn(make_float2(a, b));
    return *reinterpret_cast<uint32_t*>(&h);
}
__device__ __forceinline__ float bf2f(uint16_t u) {
    return __uint_as_float(((uint32_t)u) << 16);
}

union BF8 { bf16x8 v; uint32_t u[4]; };

__device__ __forceinline__ bf16x8 pack8v(f32x4 lo, f32x4 hi) {
    BF8 r;
    r.u[0] = pk2(lo[0], lo[1]); r.u[1] = pk2(lo[2], lo[3]);
    r.u[2] = pk2(hi[0], hi[1]); r.u[3] = pk2(hi[2], hi[3]);
    return r.v;
}
__device__ __forceinline__ bf16x8 ldf32x8_mask(const float* rowp, int base, int limit) {
    BF8 r;
#pragma unroll
    for (int h = 0; h < 4; ++h) {
        const int k0 = base + 2 * h;
        const float a = (k0     < limit) ? rowp[k0]     : 0.f;
        const float b = (k0 + 1 < limit) ? rowp[k0 + 1] : 0.f;
        r.u[h] = pk2(a, b);
    }
    return r.v;
}

template<int N> __device__ __forceinline__ void waitcnt_vm() {
    asm volatile("s_waitcnt vmcnt(%0)" :: "n"(N) : "memory");
    __builtin_amdgcn_sched_barrier(0);
}

// ---------------------------------------------------------------------------
// prep: permuted-K transposed weights (bf16).
// k' [0,160): Apre (feat 64 | text 96)  -> orig Wproj rows 64..223
// k' [160,192): numeric (10 valid)      -> Wnum rows 0..9
// k' [192,224): word300 tail (12 valid) -> Wproj rows 512..523
// k' [224,288): id                      -> Wproj rows 0..63
// k' [288,576): word300 cols 0..287     -> Wproj rows 224..511
// k' [576,1344): sent768 (items)        -> Wproj rows 524..1291
// ---------------------------------------------------------------------------
__global__ void prep_kernel(const float* __restrict__ Wproj_u, const float* __restrict__ Wnum_u,
                            const float* __restrict__ Wproj_i, const float* __restrict__ Wnum_i,
                            const float* __restrict__ Wv0, const float* __restrict__ Ww0,
                            uint16_t* __restrict__ WTU, uint16_t* __restrict__ WTI,
                            uint16_t* __restrict__ WvT, uint16_t* __restrict__ WwT)
{
    const int idx = blockIdx.x * 256 + threadIdx.x;   // exactly 135168
    if (idx < 36864) {
        const int d = idx / 576, kp = idx - d * 576;
        float v = 0.f;
        if (kp < 160)      v = Wproj_u[(64 + kp) * 64 + d];
        else if (kp < 192) { const int j = kp - 160; if (j < 10) v = Wnum_u[j * 64 + d]; }
        else if (kp < 224) { const int j = kp - 192; if (j < 12) v = Wproj_u[(512 + j) * 64 + d]; }
        else if (kp < 288) v = Wproj_u[(kp - 224) * 64 + d];
        else               v = Wproj_u[(224 + kp - 288) * 64 + d];
        WTU[d * 576 + kp] = f2bf(v);
    } else if (idx < 122880) {
        const int i2 = idx - 36864;
        const int d = i2 / 1344, kp = i2 - d * 1344;
        float v = 0.f;
        if (kp < 160)      v = Wproj_i[(64 + kp) * 64 + d];
        else if (kp < 192) { const int j = kp - 160; if (j < 10) v = Wnum_i[j * 64 + d]; }
        else if (kp < 224) { const int j = kp - 192; if (j < 12) v = Wproj_i[(512 + j) * 64 + d]; }
        else if (kp < 288) v = Wproj_i[(kp - 224) * 64 + d];
        else if (kp < 576) v = Wproj_i[(224 + kp - 288) * 64 + d];
        else               v = Wproj_i[(524 + kp - 576) * 64 + d];
        WTI[d * 1344 + kp] = f2bf(v);
    } else {
        const int i2 = idx - 122880;
        if (i2 < 4096) { const int d = i2 >> 6, k = i2 & 63;  WvT[d * 64 + k]  = f2bf(Wv0[k * 64 + d]); }
        else           { const int j = i2 - 4096;
                         const int d = j >> 7, k = j & 127;   WwT[d * 128 + k] = f2bf(Ww0[k * 64 + d]); }
    }
}

// ---------------------------------------------------------------------------
// gpack: gathered segments -> A_pre[node][160] bf16 (8 threads per node).
// ---------------------------------------------------------------------------
__global__ __launch_bounds__(256) void gpack_kernel(
    const int* __restrict__ ufi, const int* __restrict__ ifi,
    const int* __restrict__ uti, const int* __restrict__ iti,
    const float* __restrict__ ufe, const float* __restrict__ ife,
    const float* __restrict__ wemb,
    uint16_t* __restrict__ Apre)
{
    const int gid  = blockIdx.x * 256 + threadIdx.x;
    const int node = gid >> 3;
    const int d0   = gid & 7;
    if (node >= N_NODE) return;
    const bool item = node >= N_USER;
    const int nloc  = item ? node - N_USER : node;
    const int*   fidx = (item ? ifi : ufi) + (size_t)nloc * 10;
    const int*   tidx = (item ? iti : uti) + (size_t)nloc * 24;
    const float* fe   = item ? ife : ufe;
    uint16_t* out = Apre + (size_t)node * 160;

    {
        f32x4 s0 = {0, 0, 0, 0}, s1 = {0, 0, 0, 0};
#pragma unroll
        for (int j = 0; j < 10; ++j) {
            const float* p = fe + (size_t)fidx[j] * 64 + 8 * d0;
            s0 += *(const f32x4*)p;
            s1 += *(const f32x4*)(p + 4);
        }
        s0 *= 0.1f; s1 *= 0.1f;
        uint4 o = make_uint4(pk2(s0[0], s0[1]), pk2(s0[2], s0[3]),
                             pk2(s1[0], s1[1]), pk2(s1[2], s1[3]));
        *(uint4*)(out + 8 * d0) = o;
    }
#pragma unroll
    for (int s = 0; s < 3; ++s) {
        f32x4 a = {0, 0, 0, 0};
#pragma unroll
        for (int j = 0; j < 8; ++j) {
            const float* p = wemb + (size_t)tidx[s * 8 + j] * 32 + 4 * d0;
            a += *(const f32x4*)p;
        }
        a *= 0.125f;
        *(uint2*)(out + 64 + 32 * s + 4 * d0) = make_uint2(pk2(a[0], a[1]), pk2(a[2], a[3]));
    }
}

// ---------------------------------------------------------------------------
// pgemm: per-wave pipelined GEMM.
// A: global_load_lds, double-buffered (2x2KB/wave, 16KB/block), XOR-swizzled.
// B: plain register loads, double-prefetched one chunk ahead (b0/b1 named
//    sets, loop unrolled x2). Issue bundle per chunk = {2 A-lds + 4 B-reg};
//    counted vmcnt(6) => chunk c fully landed while c+1 is in flight.
// No barriers (each wave stages/computes only its own 16 rows).
// ---------------------------------------------------------------------------
__global__ __launch_bounds__(256, 4) void pgemm_kernel(
    const uint16_t* __restrict__ Apre,
    const float* __restrict__ u_id,  const float* __restrict__ i_id,
    const float* __restrict__ uw300, const float* __restrict__ iw300,
    const float* __restrict__ is768,
    const float* __restrict__ unum,  const float* __restrict__ inum,
    const uint16_t* __restrict__ WTU, const uint16_t* __restrict__ WTI,
    const float* __restrict__ bproj_u, const float* __restrict__ bnum_u,
    const float* __restrict__ bproj_i, const float* __restrict__ bnum_i,
    uint16_t* __restrict__ xout)
{
    __shared__ char lds[2][4][2048];   // [buf][wave][A 2KB] = 16 KB

    const int t = threadIdx.x;
    const int w = t >> 6, l = t & 63;
    const int l15 = l & 15, g4 = l >> 4;
    const bool item = blockIdx.x < IBLK2;
    const int tile  = item ? blockIdx.x : (blockIdx.x - IBLK2);
    const int ntype = item ? M_ITEM : N_USER;
    const int nb    = tile * 64;
    const int NC    = item ? 35 : 11;   // both odd

    const float* idp = item ? i_id  : u_id;
    const float* w3p = item ? iw300 : uw300;
    const float* nmp = item ? inum  : unum;
    const uint16_t* WT = item ? WTI : WTU;
    const int KP       = item ? 1344 : 576;

    f32x4 acc[4] = {};
    const uint16_t* WTb = WT + (size_t)l15 * KP + g4 * 8;    // prologue B (global)
    const uint16_t* WTfrag = WTb;                            // loop B fragments

    auto MM = [&](bf16x8 af2, int kb) {   // B direct from global (prologue only)
#pragma unroll
        for (int db = 0; db < 4; ++db) {
            const bf16x8 bfr = *reinterpret_cast<const bf16x8*>(WTb + (size_t)db * 16 * KP + kb);
            acc[db] = __builtin_amdgcn_mfma_f32_16x16x32_bf16(af2, bfr, acc[db], 0, 0, 0);
        }
    };

    // chunk c -> A source:  c<2 id | c<11 w300 | else s768
    auto stageA = [&](int bi, int c) {
        const float* base; int stride, coloff;
        if (c < 2)       { base = idp;    stride = 64;  coloff = c * 32; }
        else if (c < 11) { base = w3p;    stride = 300; coloff = (c - 2) * 32; }
        else             { base = is768;  stride = 768; coloff = (c - 11) * 32; }
        char* wbase = &lds[bi][w][0];
#pragma unroll
        for (int j = 0; j < 2; ++j) {
            const int rl   = j * 8 + (l >> 3);
            const int nn   = nb + w * 16 + rl;
            const int node = nn < ntype ? nn : (ntype - 1);
            const int swb  = ((l & 7) * 16) ^ ((rl & 7) << 4);
            const float* g = base + (size_t)node * stride + coloff + (swb >> 2);
            __builtin_amdgcn_global_load_lds((glb_u32_t*)g,
                (lds_u32_t*)(void*)(wbase + j * 1024), 16, 0, 0);
        }
    };

    auto loadB = [&](bf16x8* breg, int c) {
        const int kb = 224 + 32 * c;
#pragma unroll
        for (int i = 0; i < 4; ++i)
            breg[i] = *reinterpret_cast<const bf16x8*>(WTfrag + (size_t)i * 16 * KP + kb);
    };

    auto computeA = [&](int bi, const bf16x8* breg) {
        const char* wbase = &lds[bi][w][0];
        const int r = l15;
        const f32x4 lo = *(const f32x4*)(wbase + r * 128 + ((g4 * 32)      ^ ((r & 7) << 4)));
        const f32x4 hi = *(const f32x4*)(wbase + r * 128 + ((g4 * 32 + 16) ^ ((r & 7) << 4)));
        const bf16x8 af2 = pack8v(lo, hi);
#pragma unroll
        for (int db = 0; db < 4; ++db)
            acc[db] = __builtin_amdgcn_mfma_f32_16x16x32_bf16(af2, breg[db], acc[db], 0, 0, 0);
    };

    // ---- register-path loads issued FIRST (retire before A0/B0) ----
    const int nloc = (nb + w * 16 + l15) < ntype ? (nb + w * 16 + l15) : (ntype - 1);
    const int node = (item ? N_USER : 0) + nloc;
    const uint16_t* ap = Apre + (size_t)node * 160 + g4 * 8;
    bf16x8 af[5];
#pragma unroll
    for (int ks = 0; ks < 5; ++ks) af[ks] = *(const bf16x8*)(ap + ks * 32);
    const bf16x8 numf  = ldf32x8_mask(nmp + (size_t)nloc * 10, g4 * 8, 10);
    const bf16x8 tailf = ldf32x8_mask(w3p + (size_t)nloc * 300, 288 + g4 * 8, 300);

    // ---- issue chunk 0 (A->lds, B->regs), prologue MFMAs overlap flight ----
    bf16x8 b0[4], b1[4];
    stageA(0, 0);
    loadB(b0, 0);
#pragma unroll
    for (int ks = 0; ks < 5; ++ks) MM(af[ks], ks * 32);
    MM(numf, 160);
    MM(tailf, 192);

    // ---- main loop: unrolled x2, counted vmcnt(6), no barriers ----
    int c = 0;
#pragma unroll 1
    for (; c + 2 <= NC; c += 2) {
        stageA(1, c + 1); loadB(b1, c + 1);
        waitcnt_vm<6>();                      // chunk c landed (c+1 in flight)
        computeA(0, b0);
        if (c + 2 < NC) { stageA(0, c + 2); loadB(b0, c + 2); waitcnt_vm<6>(); }
        else            { waitcnt_vm<0>(); }
        computeA(1, b1);
    }
    if (c < NC) {                             // NC odd: last chunk in buf0/b0
        waitcnt_vm<0>();
        computeA(0, b0);
    }

    // ---- epilogue: row = g4*4+r (node-in-64), col d = db*16+l15 ----
    const int nb_out = nb + w * 16 + g4 * 4;
    const float* bp = item ? bproj_i : bproj_u;
    const float* bn = item ? bnum_i  : bnum_u;
    uint16_t* xo = xout + (size_t)(item ? N_USER : 0) * 64;
#pragma unroll
    for (int db = 0; db < 4; ++db) {
        const int d = db * 16 + l15;
        const float bias = bp[d] + bn[d];
#pragma unroll
        for (int r = 0; r < 4; ++r) {
            const int nn = nb_out + r;
            if (nn < ntype) xo[(size_t)nn * 64 + d] = f2bf(acc[db][r] + bias);
        }
    }
}

// ---------------------------------------------------------------------------
// xv = x @ Wv0 + bv0   (bf16 in/out, per node)
// ---------------------------------------------------------------------------
__global__ __launch_bounds__(256) void xv_kernel(
    const uint16_t* __restrict__ x, const uint16_t* __restrict__ WvT,
    const float* __restrict__ bv, uint16_t* __restrict__ xv, int n)
{
    const int t = threadIdx.x;
    const int w = t >> 6, l = t & 63, l15 = l & 15, g4 = l >> 4;
    const int node = blockIdx.x * 64 + w * 16 + l15;
    const int node_c = node < n ? node : n - 1;

    f32x4 acc[4] = {};
    const uint16_t* WTb = WvT + l15 * 64 + g4 * 8;
#pragma unroll
    for (int ks = 0; ks < 2; ++ks) {
        const bf16x8 af = *reinterpret_cast<const bf16x8*>(x + (size_t)node_c * 64 + ks * 32 + g4 * 8);
#pragma unroll
        for (int db = 0; db < 4; ++db) {
            const bf16x8 bfr = *reinterpret_cast<const bf16x8*>(WTb + db * 16 * 64 + ks * 32);
            acc[db] = __builtin_amdgcn_mfma_f32_16x16x32_bf16(af, bfr, acc[db], 0, 0, 0);
        }
    }
    const int node_base = blockIdx.x * 64 + w * 16 + g4 * 4;
#pragma unroll
    for (int db = 0; db < 4; ++db) {
        const int d = db * 16 + l15;
        const float bias = bv[d];
#pragma unroll
        for (int r = 0; r < 4; ++r) {
            const int nn = node_base + r;
            if (nn < n) xv[(size_t)nn * 64 + d] = f2bf(acc[db][r] + bias);
        }
    }
}

// ---------------------------------------------------------------------------
// SAGE layer-0 (MFMA): out[r] = act( [ x[self[r]] | mean_j xv[neigh[r,j]] ] @ Ww0 + bw0 )
// ---------------------------------------------------------------------------
__global__ __launch_bounds__(256) void sage_mfma_kernel(
    const uint16_t* __restrict__ x, const uint16_t* __restrict__ xv,
    const int* __restrict__ self_idx, const int* __restrict__ neigh_idx,
    const uint16_t* __restrict__ WwT, const float* __restrict__ bw,
    uint16_t* __restrict__ out, int relu)
{
    const int t = threadIdx.x;
    const int w = t >> 6, l = t & 63, l15 = l & 15, g4 = l >> 4;
    const int r = blockIdx.x * 64 + w * 16 + l15;
    const int sidx = self_idx[r];
    const int* ni = neigh_idx + (size_t)r * S_NB;

    f32x4 acc[4] = {};
    const uint16_t* WTb = WwT + l15 * 128 + g4 * 8;

    auto MM = [&](bf16x8 af, int kb) {
#pragma unroll
        for (int db = 0; db < 4; ++db) {
            const bf16x8 bfr = *reinterpret_cast<const bf16x8*>(WTb + db * 16 * 128 + kb);
            acc[db] = __builtin_amdgcn_mfma_f32_16x16x32_bf16(af, bfr, acc[db], 0, 0, 0);
        }
    };

#pragma unroll
    for (int ks = 0; ks < 2; ++ks) {
        const bf16x8 af = *reinterpret_cast<const bf16x8*>(x + (size_t)sidx * 64 + ks * 32 + g4 * 8);
        MM(af, ks * 32);
    }
#pragma unroll
    for (int ks = 0; ks < 2; ++ks) {
        float ev[4] = {0.f, 0.f, 0.f, 0.f}, od[4] = {0.f, 0.f, 0.f, 0.f};
#pragma unroll
        for (int j = 0; j < S_NB; ++j) {
            const u32x4 v = *reinterpret_cast<const u32x4*>(xv + (size_t)ni[j] * 64 + ks * 32 + g4 * 8);
#pragma unroll
            for (int q = 0; q < 4; ++q) {
                ev[q] += __uint_as_float(v[q] << 16);
                od[q] += __uint_as_float(v[q] & 0xffff0000u);
            }
        }
        BF8 m;
#pragma unroll
        for (int q = 0; q < 4; ++q) m.u[q] = pk2(ev[q] * (1.f / S_NB), od[q] * (1.f / S_NB));
        MM(m.v, 64 + ks * 32);
    }

    const int rb = blockIdx.x * 64 + w * 16 + g4 * 4;
#pragma unroll
    for (int db = 0; db < 4; ++db) {
        const int d = db * 16 + l15;
        const float bias = bw[d];
#pragma unroll
        for (int rr = 0; rr < 4; ++rr) {
            float h = acc[db][rr] + bias;
            if (relu) h = fmaxf(h, 0.f);
            out[(size_t)(rb + rr) * 64 + d] = f2bf(h);
        }
    }
}

// ---------------------------------------------------------------------------
// Final layer (fp32 shfl GEMV, 2048 rows)
// ---------------------------------------------------------------------------
__global__ __launch_bounds__(256) void final_kernel(
    const uint16_t* __restrict__ h0, const uint16_t* __restrict__ h1,
    const float* __restrict__ Wv, const float* __restrict__ bv,
    const float* __restrict__ Ww, const float* __restrict__ bw,
    float* __restrict__ out)
{
    __shared__ float WvL[64 * 64];
    __shared__ float WwL[128 * 64];
    const int t = threadIdx.x;
    for (int i = t; i < 64 * 64; i += 256)  WvL[i] = Wv[i];
    for (int i = t; i < 128 * 64; i += 256) WwL[i] = Ww[i];
    __syncthreads();

    const int wave = t >> 6, lane = t & 63;
    const int base = blockIdx.x * 32 + wave * 8;
    const float bvl = bv[lane], bwl = bw[lane];

    for (int i = 0; i < 8; ++i) {
        const int b = base + i;
        float m = 0.f;
#pragma unroll
        for (int s = 0; s < S_NB; ++s)
            m += bf2f(h1[(size_t)(b * S_NB + s) * 64 + lane]);
        m *= (1.f / S_NB);

        float agg = bvl;
#pragma unroll 8
        for (int k = 0; k < 64; ++k)
            agg += __shfl(m, k) * WvL[k * 64 + lane];

        const float selfv = bf2f(h0[(size_t)b * 64 + lane]);
        float h = bwl;
#pragma unroll 8
        for (int k = 0; k < 64; ++k)
            h += __shfl(selfv, k) * WwL[k * 64 + lane];
#pragma unroll 8
        for (int k = 0; k < 64; ++k)
            h += __shfl(agg, k) * WwL[(64 + k) * 64 + lane];

        out[(size_t)b * 64 + lane] = h;
    }
}

// ---------------------------------------------------------------------------
extern "C" void kernel_launch(void* const* d_in, const int* in_sizes, int n_in,
                              void* d_out, int out_size, void* d_ws, size_t ws_size,
                              hipStream_t stream)
{
    const int*   seeds   = (const int*)d_in[0];
    const int*   neigh1  = (const int*)d_in[1];
    const int*   neigh2  = (const int*)d_in[2];
    const int*   ufi     = (const int*)d_in[3];
    const int*   ifi     = (const int*)d_in[4];
    const int*   uti     = (const int*)d_in[5];
    const int*   iti     = (const int*)d_in[6];
    const float* u_id    = (const float*)d_in[7];
    const float* i_id    = (const float*)d_in[8];
    const float* ufe     = (const float*)d_in[9];
    const float* ife     = (const float*)d_in[10];
    const float* wemb    = (const float*)d_in[11];
    const float* uw300   = (const float*)d_in[12];
    const float* iw300   = (const float*)d_in[13];
    const float* is768   = (const float*)d_in[14];
    const float* unum    = (const float*)d_in[15];
    const float* inum    = (const float*)d_in[16];
    const float* Wnum_u  = (const float*)d_in[17];
    const float* bnum_u  = (const float*)d_in[18];
    const float* Wnum_i  = (const float*)d_in[19];
    const float* bnum_i  = (const float*)d_in[20];
    const float* Wproj_u = (const float*)d_in[21];
    const float* bproj_u = (const float*)d_in[22];
    const float* Wproj_i = (const float*)d_in[23];
    const float* bproj_i = (const float*)d_in[24];
    const float* W_w     = (const float*)d_in[25];
    const float* b_w     = (const float*)d_in[26];
    const float* W_v     = (const float*)d_in[27];
    const float* b_v     = (const float*)d_in[28];

    // ws layout (uint16 elements):
    // WTU | WTI | WvT0 | WwT0 | xbf | UNION{ xvbf|h1bf|h0bf , A_pre }
    uint16_t* WTU  = (uint16_t*)d_ws;                       // 64*576
    uint16_t* WTI  = WTU  + 36864;                          // 64*1344
    uint16_t* WvT0 = WTI  + 86016;                          // 64*64
    uint16_t* WwT0 = WvT0 + 4096;                           // 64*128
    uint16_t* xbf  = WwT0 + 8192;                           // 150000*64
    uint16_t* xvbf = xbf  + (size_t)N_NODE * 64;
    uint16_t* h1bf = xvbf + (size_t)N_NODE * 64;
    uint16_t* h0bf = h1bf + (size_t)B_SEED * S_NB * 64;
    uint16_t* Apre = xvbf;                                  // aliases xv region; dead after pgemm
    float* outp = (float*)d_out;

    prep_kernel<<<528, 256, 0, stream>>>(
        Wproj_u, Wnum_u, Wproj_i, Wnum_i, W_v, W_w, WTU, WTI, WvT0, WwT0);

    gpack_kernel<<<(N_NODE * 8 + 255) / 256, 256, 0, stream>>>(
        ufi, ifi, uti, iti, ufe, ife, wemb, Apre);

    pgemm_kernel<<<UBLK2 + IBLK2, 256, 0, stream>>>(
        Apre, u_id, i_id, uw300, iw300, is768, unum, inum,
        WTU, WTI, bproj_u, bnum_u, bproj_i, bnum_i, xbf);

    xv_kernel<<<(N_NODE + 63) / 64, 256, 0, stream>>>(xbf, WvT0, b_v, xvbf, N_NODE);

    sage_mfma_kernel<<<(B_SEED * S_NB) / 64, 256, 0, stream>>>(
        xbf, xvbf, neigh1, neigh2, WwT0, b_w, h1bf, 1);
    sage_mfma_kernel<<<B_SEED / 64, 256, 0, stream>>>(
        xbf, xvbf, seeds, neigh1, WwT0, b_w, h0bf, 1);

    final_kernel<<<B_SEED / 32, 256, 0, stream>>>(
        h0bf, h1bf, W_v + 4096, b_v + 64, W_w + 8192, b_w + 64, outp);
}

// Round 12
// 340.223 us; speedup vs baseline: 1.0423x; 1.0423x over previous
//
#include <hip/hip_runtime.h>
#include <hip/hip_bf16.h>
#include <stdint.h>

#define N_USER 100000
#define M_ITEM 50000
#define N_NODE 150000
#define B_SEED 2048
#define S_NB 20
#define UBLK2 1563           // ceil(100000/64)
#define IBLK2 782            // ceil(50000/64)

typedef __bf16   bf16x8 __attribute__((ext_vector_type(8)));
typedef float    f32x4  __attribute__((ext_vector_type(4)));
typedef uint32_t u32x4  __attribute__((ext_vector_type(4)));

typedef __attribute__((address_space(3))) uint32_t lds_u32_t;
typedef __attribute__((address_space(1))) const uint32_t glb_u32_t;

__device__ __forceinline__ uint16_t f2bf(float f) {
    uint32_t u = __float_as_uint(f);
    return (uint16_t)((u + 0x7FFFu + ((u >> 16) & 1u)) >> 16);   // RNE
}
__device__ __forceinline__ uint32_t pk2(float a, float b) {      // packed HW cvt (RNE)
    __hip_bfloat162 h = __float22bfloat162_rn(make_float2(a, b));
    return *reinterpret_cast<uint32_t*>(&h);
}
__device__ __forceinline__ float bf2f(uint16_t u) {
    return __uint_as_float(((uint32_t)u) << 16);
}

union BF8 { bf16x8 v; uint32_t u[4]; };

__device__ __forceinline__ bf16x8 pack8v(f32x4 lo, f32x4 hi) {
    BF8 r;
    r.u[0] = pk2(lo[0], lo[1]); r.u[1] = pk2(lo[2], lo[3]);
    r.u[2] = pk2(hi[0], hi[1]); r.u[3] = pk2(hi[2], hi[3]);
    return r.v;
}
__device__ __forceinline__ bf16x8 ldf32x8_mask(const float* rowp, int base, int limit) {
    BF8 r;
#pragma unroll
    for (int h = 0; h < 4; ++h) {
        const int k0 = base + 2 * h;
        const float a = (k0     < limit) ? rowp[k0]     : 0.f;
        const float b = (k0 + 1 < limit) ? rowp[k0 + 1] : 0.f;
        r.u[h] = pk2(a, b);
    }
    return r.v;
}

// ---------------------------------------------------------------------------
// prep: permuted-K transposed weights (bf16).
// k' [0,160): Apre (feat 64 | text 96)  -> orig Wproj rows 64..223
// k' [160,192): numeric (10 valid)      -> Wnum rows 0..9
// k' [192,224): word300 tail (12 valid) -> Wproj rows 512..523
// k' [224,288): id                      -> Wproj rows 0..63
// k' [288,576): word300 cols 0..287     -> Wproj rows 224..511
// k' [576,1344): sent768 (items)        -> Wproj rows 524..1291
// ---------------------------------------------------------------------------
__global__ void prep_kernel(const float* __restrict__ Wproj_u, const float* __restrict__ Wnum_u,
                            const float* __restrict__ Wproj_i, const float* __restrict__ Wnum_i,
                            const float* __restrict__ Wv0, const float* __restrict__ Ww0,
                            uint16_t* __restrict__ WTU, uint16_t* __restrict__ WTI,
                            uint16_t* __restrict__ WvT, uint16_t* __restrict__ WwT)
{
    const int idx = blockIdx.x * 256 + threadIdx.x;   // exactly 135168
    if (idx < 36864) {
        const int d = idx / 576, kp = idx - d * 576;
        float v = 0.f;
        if (kp < 160)      v = Wproj_u[(64 + kp) * 64 + d];
        else if (kp < 192) { const int j = kp - 160; if (j < 10) v = Wnum_u[j * 64 + d]; }
        else if (kp < 224) { const int j = kp - 192; if (j < 12) v = Wproj_u[(512 + j) * 64 + d]; }
        else if (kp < 288) v = Wproj_u[(kp - 224) * 64 + d];
        else               v = Wproj_u[(224 + kp - 288) * 64 + d];
        WTU[d * 576 + kp] = f2bf(v);
    } else if (idx < 122880) {
        const int i2 = idx - 36864;
        const int d = i2 / 1344, kp = i2 - d * 1344;
        float v = 0.f;
        if (kp < 160)      v = Wproj_i[(64 + kp) * 64 + d];
        else if (kp < 192) { const int j = kp - 160; if (j < 10) v = Wnum_i[j * 64 + d]; }
        else if (kp < 224) { const int j = kp - 192; if (j < 12) v = Wproj_i[(512 + j) * 64 + d]; }
        else if (kp < 288) v = Wproj_i[(kp - 224) * 64 + d];
        else if (kp < 576) v = Wproj_i[(224 + kp - 288) * 64 + d];
        else               v = Wproj_i[(524 + kp - 576) * 64 + d];
        WTI[d * 1344 + kp] = f2bf(v);
    } else {
        const int i2 = idx - 122880;
        if (i2 < 4096) { const int d = i2 >> 6, k = i2 & 63;  WvT[d * 64 + k]  = f2bf(Wv0[k * 64 + d]); }
        else           { const int j = i2 - 4096;
                         const int d = j >> 7, k = j & 127;   WwT[d * 128 + k] = f2bf(Ww0[k * 64 + d]); }
    }
}

// ---------------------------------------------------------------------------
// gpack: gathered segments -> A_pre[node][160] bf16 (8 threads per node).
// ---------------------------------------------------------------------------
__global__ __launch_bounds__(256) void gpack_kernel(
    const int* __restrict__ ufi, const int* __restrict__ ifi,
    const int* __restrict__ uti, const int* __restrict__ iti,
    const float* __restrict__ ufe, const float* __restrict__ ife,
    const float* __restrict__ wemb,
    uint16_t* __restrict__ Apre)
{
    const int gid  = blockIdx.x * 256 + threadIdx.x;
    const int node = gid >> 3;
    const int d0   = gid & 7;
    if (node >= N_NODE) return;
    const bool item = node >= N_USER;
    const int nloc  = item ? node - N_USER : node;
    const int*   fidx = (item ? ifi : ufi) + (size_t)nloc * 10;
    const int*   tidx = (item ? iti : uti) + (size_t)nloc * 24;
    const float* fe   = item ? ife : ufe;
    uint16_t* out = Apre + (size_t)node * 160;

    {
        f32x4 s0 = {0, 0, 0, 0}, s1 = {0, 0, 0, 0};
#pragma unroll
        for (int j = 0; j < 10; ++j) {
            const float* p = fe + (size_t)fidx[j] * 64 + 8 * d0;
            s0 += *(const f32x4*)p;
            s1 += *(const f32x4*)(p + 4);
        }
        s0 *= 0.1f; s1 *= 0.1f;
        uint4 o = make_uint4(pk2(s0[0], s0[1]), pk2(s0[2], s0[3]),
                             pk2(s1[0], s1[1]), pk2(s1[2], s1[3]));
        *(uint4*)(out + 8 * d0) = o;
    }
#pragma unroll
    for (int s = 0; s < 3; ++s) {
        f32x4 a = {0, 0, 0, 0};
#pragma unroll
        for (int j = 0; j < 8; ++j) {
            const float* p = wemb + (size_t)tidx[s * 8 + j] * 32 + 4 * d0;
            a += *(const f32x4*)p;
        }
        a *= 0.125f;
        *(uint2*)(out + 64 + 32 * s + 4 * d0) = make_uint2(pk2(a[0], a[1]), pk2(a[2], a[3]));
    }
}

// ---------------------------------------------------------------------------
// pgemm: cooperative double-buffered LDS staging (r8 structure), 64-f32-col
// chunks (16 KB/buffer), XOR-swizzled 16B granule on global src + ds_read.
// Chunk map: c==0 id | c 1..4 w300 cols (c-1)*64 | c>=5 s768 cols (c-5)*64.
// Reg-path prologue: Apre (k'0..160), numeric (160), w300 tail 288..299 (192),
// w300 cols 256..287 (544).
// ---------------------------------------------------------------------------
__global__ __launch_bounds__(256, 6) void pgemm_kernel(
    const uint16_t* __restrict__ Apre,
    const float* __restrict__ u_id,  const float* __restrict__ i_id,
    const float* __restrict__ uw300, const float* __restrict__ iw300,
    const float* __restrict__ is768,
    const float* __restrict__ unum,  const float* __restrict__ inum,
    const uint16_t* __restrict__ WTU, const uint16_t* __restrict__ WTI,
    const float* __restrict__ bproj_u, const float* __restrict__ bnum_u,
    const float* __restrict__ bproj_i, const float* __restrict__ bnum_i,
    uint16_t* __restrict__ xout)
{
    __shared__ float buf[2][4096];   // 2 x (64 rows x 64 f32) = 32 KB

    const int t = threadIdx.x;
    const int w = t >> 6, l = t & 63;
    const int l15 = l & 15, g4 = l >> 4;
    const bool item = blockIdx.x < IBLK2;
    const int tile  = item ? blockIdx.x : (blockIdx.x - IBLK2);
    const int ntype = item ? M_ITEM : N_USER;
    const int nb    = tile * 64;
    const int NC    = item ? 17 : 5;

    const float* idp = item ? i_id  : u_id;
    const float* w3p = item ? iw300 : uw300;
    const float* nmp = item ? inum  : unum;
    const uint16_t* WT = item ? WTI : WTU;
    const int KP       = item ? 1344 : 576;

    f32x4 acc[4] = {};
    const uint16_t* WTb = WT + (size_t)l15 * KP + g4 * 8;

    auto MM = [&](bf16x8 af2, int kb) {
#pragma unroll
        for (int db = 0; db < 4; ++db) {
            const bf16x8 bfr = *reinterpret_cast<const bf16x8*>(WTb + (size_t)db * 16 * KP + kb);
            acc[db] = __builtin_amdgcn_mfma_f32_16x16x32_bf16(af2, bfr, acc[db], 0, 0, 0);
        }
    };

    auto stage = [&](int bi, int c) {
        const float* base; int stride, coloff;
        if (c == 0)      { base = idp;   stride = 64;  coloff = 0; }
        else if (c < 5)  { base = w3p;   stride = 300; coloff = (c - 1) * 64; }
        else             { base = is768; stride = 768; coloff = (c - 5) * 64; }
        char* wbase = (char*)&buf[bi][0] + w * 4096;
#pragma unroll
        for (int j = 0; j < 4; ++j) {
            const int row  = j * 4 + (l >> 4);
            const int nn   = nb + w * 16 + row;
            const int node = nn < ntype ? nn : (ntype - 1);
            const int swb  = ((l & 15) * 16) ^ ((row & 7) << 4);   // swizzled byte-in-row
            const float* g = base + (size_t)node * stride + coloff + (swb >> 2);
            __builtin_amdgcn_global_load_lds((glb_u32_t*)g,
                (lds_u32_t*)(void*)(wbase + j * 1024), 16, 0, 0);
        }
    };

    auto compute = [&](int bi, int kb0) {
        const char* wbase = (const char*)&buf[bi][0] + w * 4096;
        const int r = l15;
#pragma unroll
        for (int ks = 0; ks < 2; ++ks) {
            const f32x4 lo = *(const f32x4*)(wbase + r * 256 + ((ks * 128 + g4 * 32)      ^ ((r & 7) << 4)));
            const f32x4 hi = *(const f32x4*)(wbase + r * 256 + ((ks * 128 + g4 * 32 + 16) ^ ((r & 7) << 4)));
            MM(pack8v(lo, hi), kb0 + ks * 32);
        }
    };

    // ---- register-path loads issued FIRST ----
    const int nloc = (nb + w * 16 + l15) < ntype ? (nb + w * 16 + l15) : (ntype - 1);
    const int node = (item ? N_USER : 0) + nloc;
    const uint16_t* ap = Apre + (size_t)node * 160 + g4 * 8;
    bf16x8 af[5];
#pragma unroll
    for (int ks = 0; ks < 5; ++ks) af[ks] = *(const bf16x8*)(ap + ks * 32);
    const float* wr = w3p + (size_t)nloc * 300;
    const bf16x8 numf  = ldf32x8_mask(nmp + (size_t)nloc * 10, g4 * 8, 10);
    const bf16x8 tailf = ldf32x8_mask(wr, 288 + g4 * 8, 300);
    const bf16x8 w300c = pack8v(*(const f32x4*)(wr + 256 + g4 * 8),
                                *(const f32x4*)(wr + 260 + g4 * 8));

    // ---- stage chunk 0; prologue MFMAs (reg path) overlap its flight ----
    stage(0, 0);
#pragma unroll
    for (int ks = 0; ks < 5; ++ks) MM(af[ks], ks * 32);
    MM(numf, 160);
    MM(tailf, 192);
    MM(w300c, 544);

    // ---- staged main loop (two-barrier structure, halved chunk count) ----
    for (int c = 0; c < NC; ++c) {
        if (c + 1 < NC) stage((c + 1) & 1, c + 1);
        __syncthreads();
        compute(c & 1, (c < 5) ? 224 + 64 * c : 576 + 64 * (c - 5));
        __syncthreads();
    }

    // ---- epilogue: row = g4*4+r (node-in-64), col d = db*16+l15 ----
    const int nb_out = nb + w * 16 + g4 * 4;
    const float* bp = item ? bproj_i : bproj_u;
    const float* bn = item ? bnum_i  : bnum_u;
    uint16_t* xo = xout + (size_t)(item ? N_USER : 0) * 64;
#pragma unroll
    for (int db = 0; db < 4; ++db) {
        const int d = db * 16 + l15;
        const float bias = bp[d] + bn[d];
#pragma unroll
        for (int r = 0; r < 4; ++r) {
            const int nn = nb_out + r;
            if (nn < ntype) xo[(size_t)nn * 64 + d] = f2bf(acc[db][r] + bias);
        }
    }
}

// ---------------------------------------------------------------------------
// xv = x @ Wv0 + bv0   (bf16 in/out, per node)
// ---------------------------------------------------------------------------
__global__ __launch_bounds__(256) void xv_kernel(
    const uint16_t* __restrict__ x, const uint16_t* __restrict__ WvT,
    const float* __restrict__ bv, uint16_t* __restrict__ xv, int n)
{
    const int t = threadIdx.x;
    const int w = t >> 6, l = t & 63, l15 = l & 15, g4 = l >> 4;
    const int node = blockIdx.x * 64 + w * 16 + l15;
    const int node_c = node < n ? node : n - 1;

    f32x4 acc[4] = {};
    const uint16_t* WTb = WvT + l15 * 64 + g4 * 8;
#pragma unroll
    for (int ks = 0; ks < 2; ++ks) {
        const bf16x8 af = *reinterpret_cast<const bf16x8*>(x + (size_t)node_c * 64 + ks * 32 + g4 * 8);
#pragma unroll
        for (int db = 0; db < 4; ++db) {
            const bf16x8 bfr = *reinterpret_cast<const bf16x8*>(WTb + db * 16 * 64 + ks * 32);
            acc[db] = __builtin_amdgcn_mfma_f32_16x16x32_bf16(af, bfr, acc[db], 0, 0, 0);
        }
    }
    const int node_base = blockIdx.x * 64 + w * 16 + g4 * 4;
#pragma unroll
    for (int db = 0; db < 4; ++db) {
        const int d = db * 16 + l15;
        const float bias = bv[d];
#pragma unroll
        for (int r = 0; r < 4; ++r) {
            const int nn = node_base + r;
            if (nn < n) xv[(size_t)nn * 64 + d] = f2bf(acc[db][r] + bias);
        }
    }
}

// ---------------------------------------------------------------------------
// Fused SAGE layer-0 (both h1 and h0 in one launch):
// rows [0,40960): h1 (self=neigh1[r], neigh=neigh2[r*20..])
// rows [40960,43008): h0 (self=seeds[r-40960], neigh=neigh1[(r-40960)*20..])
// Branch is wave-uniform (40960 = 2560*16).
// ---------------------------------------------------------------------------
__global__ __launch_bounds__(256) void sage_fused_kernel(
    const uint16_t* __restrict__ x, const uint16_t* __restrict__ xv,
    const int* __restrict__ seeds, const int* __restrict__ neigh1,
    const int* __restrict__ neigh2,
    const uint16_t* __restrict__ WwT, const float* __restrict__ bw,
    uint16_t* __restrict__ h1, uint16_t* __restrict__ h0)
{
    const int t = threadIdx.x;
    const int w = t >> 6, l = t & 63, l15 = l & 15, g4 = l >> 4;
    const int rbase = blockIdx.x * 64 + w * 16;
    const bool is1 = rbase < 40960;               // wave-uniform
    const int r = rbase + l15;
    const int sidx = is1 ? neigh1[r] : seeds[r - 40960];
    const int* ni = is1 ? (neigh2 + (size_t)r * S_NB)
                        : (neigh1 + (size_t)(r - 40960) * S_NB);

    f32x4 acc[4] = {};
    const uint16_t* WTb = WwT + l15 * 128 + g4 * 8;

    auto MM = [&](bf16x8 af, int kb) {
#pragma unroll
        for (int db = 0; db < 4; ++db) {
            const bf16x8 bfr = *reinterpret_cast<const bf16x8*>(WTb + db * 16 * 128 + kb);
            acc[db] = __builtin_amdgcn_mfma_f32_16x16x32_bf16(af, bfr, acc[db], 0, 0, 0);
        }
    };

#pragma unroll
    for (int ks = 0; ks < 2; ++ks) {
        const bf16x8 af = *reinterpret_cast<const bf16x8*>(x + (size_t)sidx * 64 + ks * 32 + g4 * 8);
        MM(af, ks * 32);
    }
#pragma unroll
    for (int ks = 0; ks < 2; ++ks) {
        float ev[4] = {0.f, 0.f, 0.f, 0.f}, od[4] = {0.f, 0.f, 0.f, 0.f};
#pragma unroll
        for (int j = 0; j < S_NB; ++j) {
            const u32x4 v = *reinterpret_cast<const u32x4*>(xv + (size_t)ni[j] * 64 + ks * 32 + g4 * 8);
#pragma unroll
            for (int q = 0; q < 4; ++q) {
                ev[q] += __uint_as_float(v[q] << 16);
                od[q] += __uint_as_float(v[q] & 0xffff0000u);
            }
        }
        BF8 m;
#pragma unroll
        for (int q = 0; q < 4; ++q) m.u[q] = pk2(ev[q] * (1.f / S_NB), od[q] * (1.f / S_NB));
        MM(m.v, 64 + ks * 32);
    }

    const int rb = blockIdx.x * 64 + w * 16 + g4 * 4;
    uint16_t* ob = is1 ? h1 : h0;
    const int rowoff = is1 ? 0 : 40960;
#pragma unroll
    for (int db = 0; db < 4; ++db) {
        const int d = db * 16 + l15;
        const float bias = bw[d];
#pragma unroll
        for (int rr = 0; rr < 4; ++rr) {
            const float h = fmaxf(acc[db][rr] + bias, 0.f);
            ob[(size_t)(rb + rr - rowoff) * 64 + d] = f2bf(h);
        }
    }
}

// ---------------------------------------------------------------------------
// Final layer (fp32 shfl GEMV, 2048 rows)
// ---------------------------------------------------------------------------
__global__ __launch_bounds__(256) void final_kernel(
    const uint16_t* __restrict__ h0, const uint16_t* __restrict__ h1,
    const float* __restrict__ Wv, const float* __restrict__ bv,
    const float* __restrict__ Ww, const float* __restrict__ bw,
    float* __restrict__ out)
{
    __shared__ float WvL[64 * 64];
    __shared__ float WwL[128 * 64];
    const int t = threadIdx.x;
    for (int i = t; i < 64 * 64; i += 256)  WvL[i] = Wv[i];
    for (int i = t; i < 128 * 64; i += 256) WwL[i] = Ww[i];
    __syncthreads();

    const int wave = t >> 6, lane = t & 63;
    const int base = blockIdx.x * 32 + wave * 8;
    const float bvl = bv[lane], bwl = bw[lane];

    for (int i = 0; i < 8; ++i) {
        const int b = base + i;
        float m = 0.f;
#pragma unroll
        for (int s = 0; s < S_NB; ++s)
            m += bf2f(h1[(size_t)(b * S_NB + s) * 64 + lane]);
        m *= (1.f / S_NB);

        float agg = bvl;
#pragma unroll 8
        for (int k = 0; k < 64; ++k)
            agg += __shfl(m, k) * WvL[k * 64 + lane];

        const float selfv = bf2f(h0[(size_t)b * 64 + lane]);
        float h = bwl;
#pragma unroll 8
        for (int k = 0; k < 64; ++k)
            h += __shfl(selfv, k) * WwL[k * 64 + lane];
#pragma unroll 8
        for (int k = 0; k < 64; ++k)
            h += __shfl(agg, k) * WwL[(64 + k) * 64 + lane];

        out[(size_t)b * 64 + lane] = h;
    }
}

// ---------------------------------------------------------------------------
extern "C" void kernel_launch(void* const* d_in, const int* in_sizes, int n_in,
                              void* d_out, int out_size, void* d_ws, size_t ws_size,
                              hipStream_t stream)
{
    const int*   seeds   = (const int*)d_in[0];
    const int*   neigh1  = (const int*)d_in[1];
    const int*   neigh2  = (const int*)d_in[2];
    const int*   ufi     = (const int*)d_in[3];
    const int*   ifi     = (const int*)d_in[4];
    const int*   uti     = (const int*)d_in[5];
    const int*   iti     = (const int*)d_in[6];
    const float* u_id    = (const float*)d_in[7];
    const float* i_id    = (const float*)d_in[8];
    const float* ufe     = (const float*)d_in[9];
    const float* ife     = (const float*)d_in[10];
    const float* wemb    = (const float*)d_in[11];
    const float* uw300   = (const float*)d_in[12];
    const float* iw300   = (const float*)d_in[13];
    const float* is768   = (const float*)d_in[14];
    const float* unum    = (const float*)d_in[15];
    const float* inum    = (const float*)d_in[16];
    const float* Wnum_u  = (const float*)d_in[17];
    const float* bnum_u  = (const float*)d_in[18];
    const float* Wnum_i  = (const float*)d_in[19];
    const float* bnum_i  = (const float*)d_in[20];
    const float* Wproj_u = (const float*)d_in[21];
    const float* bproj_u = (const float*)d_in[22];
    const float* Wproj_i = (const float*)d_in[23];
    const float* bproj_i = (const float*)d_in[24];
    const float* W_w     = (const float*)d_in[25];
    const float* b_w     = (const float*)d_in[26];
    const float* W_v     = (const float*)d_in[27];
    const float* b_v     = (const float*)d_in[28];

    // ws layout (uint16 elements):
    // WTU | WTI | WvT0 | WwT0 | xbf | UNION{ xvbf|h1bf|h0bf , A_pre }
    uint16_t* WTU  = (uint16_t*)d_ws;                       // 64*576
    uint16_t* WTI  = WTU  + 36864;                          // 64*1344
    uint16_t* WvT0 = WTI  + 86016;                          // 64*64
    uint16_t* WwT0 = WvT0 + 4096;                           // 64*128
    uint16_t* xbf  = WwT0 + 8192;                           // 150000*64
    uint16_t* xvbf = xbf  + (size_t)N_NODE * 64;
    uint16_t* h1bf = xvbf + (size_t)N_NODE * 64;
    uint16_t* h0bf = h1bf + (size_t)B_SEED * S_NB * 64;
    uint16_t* Apre = xvbf;                                  // aliases xv region; dead after pgemm
    float* outp = (float*)d_out;

    prep_kernel<<<528, 256, 0, stream>>>(
        Wproj_u, Wnum_u, Wproj_i, Wnum_i, W_v, W_w, WTU, WTI, WvT0, WwT0);

    gpack_kernel<<<(N_NODE * 8 + 255) / 256, 256, 0, stream>>>(
        ufi, ifi, uti, iti, ufe, ife, wemb, Apre);

    pgemm_kernel<<<UBLK2 + IBLK2, 256, 0, stream>>>(
        Apre, u_id, i_id, uw300, iw300, is768, unum, inum,
        WTU, WTI, bproj_u, bnum_u, bproj_i, bnum_i, xbf);

    xv_kernel<<<(N_NODE + 63) / 64, 256, 0, stream>>>(xbf, WvT0, b_v, xvbf, N_NODE);

    sage_fused_kernel<<<672, 256, 0, stream>>>(
        xbf, xvbf, seeds, neigh1, neigh2, WwT0, b_w, h1bf, h0bf);

    final_kernel<<<B_SEED / 32, 256, 0, stream>>>(
        h0bf, h1bf, W_v + 4096, b_v + 64, W_w + 8192, b_w + 64, outp);
}